// Round 1
// baseline (204.952 us; speedup 1.0000x reference)
//
#include <hip/hip_runtime.h>
#include <hip/hip_bf16.h>
#include <math.h>

#define BS 1024
#define D 128
#define NP 100000
#define PROWS 100096              // padded to multiple of 128 (96 zero rows)
#define CH 128                    // proxies per chunk/block
#define NCH (PROWS / CH)          // 782
#define NSLICE 16                 // rowsum slices (atomic contention / 16)
#define LOG2E 1.44269504088896340736f

typedef float f32x4 __attribute__((ext_vector_type(4)));
typedef float f32x16 __attribute__((ext_vector_type(16)));
typedef __bf16 bf16x8 __attribute__((ext_vector_type(8)));
typedef unsigned short u16x8 __attribute__((ext_vector_type(8)));

#if defined(__has_builtin)
#if __has_builtin(__builtin_amdgcn_exp2f)
#define FAST_EXP2(x) __builtin_amdgcn_exp2f(x)
#endif
#endif
#ifndef FAST_EXP2
#define FAST_EXP2(x) exp2f(x)
#endif

static __device__ __forceinline__ unsigned short f2bf(float x) {
    unsigned int u = __float_as_uint(x);
    return (unsigned short)((u + 0x7fffu + ((u >> 16) & 1u)) >> 16);  // RNE
}

// ---------- kernel 1: batch -> bf16 A, d_pos; zero rowsum slices + out ----
__global__ __launch_bounds__(256) void prep_kernel(
    const float* __restrict__ batch, const float* __restrict__ proxies,
    const int* __restrict__ labels, unsigned short* __restrict__ A,
    float* __restrict__ d_pos, float* __restrict__ rowsum,
    float* __restrict__ out)
{
    // zero the 16x1024 rowsum slices (128 blocks x 128 entries)
    if (threadIdx.x < 128) rowsum[blockIdx.x * 128 + threadIdx.x] = 0.f;
    if (blockIdx.x == 0 && threadIdx.x == 0) out[0] = 0.f;

    int wave = threadIdx.x >> 6, lane = threadIdx.x & 63;
    int sub = lane >> 5, c = lane & 31;
    int row = blockIdx.x * 8 + wave * 2 + sub;   // 0..1023
    float4 v = *(const float4*)(batch + (size_t)row * D + c * 4);
    float ss = v.x*v.x + v.y*v.y + v.z*v.z + v.w*v.w;
    #pragma unroll
    for (int m = 1; m < 32; m <<= 1) ss += __shfl_xor(ss, m, 64);
    float sc = 3.0f / fmaxf(sqrtf(ss), 1e-12f);
    ushort4 pk;
    pk.x = f2bf(v.x*sc); pk.y = f2bf(v.y*sc);
    pk.z = f2bf(v.z*sc); pk.w = f2bf(v.w*sc);
    *(ushort4*)(A + (size_t)row * D + c * 4) = pk;
    // d_pos in fp32: 18 - 2*(b.p_label)
    int lab = labels[row];
    float4 p4 = *(const float4*)(proxies + (size_t)lab * D + c * 4);
    float ps = p4.x*p4.x + p4.y*p4.y + p4.z*p4.z + p4.w*p4.w;
    #pragma unroll
    for (int m = 1; m < 32; m <<= 1) ps += __shfl_xor(ps, m, 64);
    float psc = 3.0f / fmaxf(sqrtf(ps), 1e-12f);
    float dt = (v.x*sc)*(p4.x*psc) + (v.y*sc)*(p4.y*psc)
             + (v.z*sc)*(p4.z*psc) + (v.w*sc)*(p4.w*psc);
    #pragma unroll
    for (int m = 1; m < 32; m <<= 1) dt += __shfl_xor(dt, m, 64);
    if (c == 0) d_pos[row] = 18.0f - 2.0f * dt;
}

// ---------- kernel 2: fused proxy-norm + GEMM + exp row-sums --------------
// 512 threads (8 waves), block = 128 proxies staged into XOR-swizzled LDS.
// Restructured around mfma_f32_32x32x16_bf16 for 2x FLOP per operand byte
// and a SMALL per-wave register set (B-cache 32 + A-frag 32 + acc 16), so
// __launch_bounds__(512,4) -> 4 waves/SIMD -> 2 blocks/CU (double the old
// occupancy). Each wave caches 32 batch columns x K=128 in registers
// (loaded once per outer iter from the L2-resident bf16 A matrix) and
// streams the 4 proxy subtiles from LDS via swizzled ds_read_b128.
// One atomicAdd per wave per outer iteration (rs accumulated across the
// 4 proxy subtiles in-register).
__global__ __launch_bounds__(512, 4) void main_kernel(
    const float* __restrict__ proxies,
    const unsigned short* __restrict__ Abat,
    float* __restrict__ rowsum)          // [NSLICE][BS]
{
    __shared__ unsigned short Plds[CH * D];   // 32 KB
    const int tid = threadIdx.x;
    const int lane = tid & 63;
    const int wave = tid >> 6;
    const int l31 = lane & 31, hi = lane >> 5;
    const int chunk = blockIdx.x;

    // ---- staging: r = tid>>2 (0..127), q = tid&3 (32 floats each) --------
    {
        int r = tid >> 2, q = tid & 3;
        int pidx = chunk * CH + r;
        const float* src = proxies + (size_t)pidx * D + q * 32;
        float ss = 0.f;
        if (pidx < NP) {
            #pragma unroll
            for (int j = 0; j < 8; ++j) {
                float4 v = *(const float4*)(src + j * 4);
                ss += v.x*v.x + v.y*v.y + v.z*v.z + v.w*v.w;
            }
        }
        ss += __shfl_xor(ss, 1, 64);             // combine 4 quarters
        ss += __shfl_xor(ss, 2, 64);
        float sc = 3.0f / fmaxf(sqrtf(ss), 1e-12f);
        #pragma unroll
        for (int i2 = 0; i2 < 4; ++i2) {
            u16x8 w = (u16x8){0,0,0,0,0,0,0,0};
            if (pidx < NP) {
                float4 a = *(const float4*)(src + i2 * 8);      // L2 hit
                float4 b = *(const float4*)(src + i2 * 8 + 4);
                w[0] = f2bf(a.x*sc); w[1] = f2bf(a.y*sc);
                w[2] = f2bf(a.z*sc); w[3] = f2bf(a.w*sc);
                w[4] = f2bf(b.x*sc); w[5] = f2bf(b.y*sc);
                w[6] = f2bf(b.z*sc); w[7] = f2bf(b.w*sc);
            }
            int cl = q * 4 + i2;                 // 16B chunk index in row
            *(u16x8*)((char*)Plds + r * 256 + ((cl ^ (r & 15)) << 4)) = w;
        }
    }
    __syncthreads();

    const float c1 = 2.0f * LOG2E, c0 = -18.0f * LOG2E;
    float* rs_base = rowsum + (size_t)(chunk & (NSLICE - 1)) * BS;
    const int rx = l31 & 15;                     // swizzle key for A reads

    #pragma unroll 1
    for (int outer = 0; outer < 4; ++outer) {
        // this wave's 32 batch columns for this pass
        const int col0 = outer * 256 + wave * 32;
        // B-cache: 32 cols x K=128 -> 8 x bf16x8 = 32 VGPRs, loaded once.
        // lane layout per K-16 step s: col = l31, k = s*16 + hi*8 + j
        const unsigned short* bp = Abat + (size_t)(col0 + l31) * D + hi * 8;
        bf16x8 Bf[8];
        #pragma unroll
        for (int s = 0; s < 8; ++s)
            Bf[s] = *(const bf16x8*)(bp + s * 16);

        float rs = 0.f;
        #pragma unroll
        for (int st = 0; st < 4; ++st) {
            // A-frags for proxy subtile st: row = st*32 + l31,
            // k = s*16 + hi*8 + j  (16B chunk cl = s*2+hi, XOR-swizzled)
            const char* arow = (const char*)Plds + (st * 32 + l31) * 256;
            bf16x8 Af[8];
            #pragma unroll
            for (int s = 0; s < 8; ++s)
                Af[s] = *(const bf16x8*)(arow + (((s * 2 + hi) ^ rx) << 4));
            f32x16 acc = {0.f,0.f,0.f,0.f,0.f,0.f,0.f,0.f,
                          0.f,0.f,0.f,0.f,0.f,0.f,0.f,0.f};
            #pragma unroll
            for (int s = 0; s < 8; ++s)
                acc = __builtin_amdgcn_mfma_f32_32x32x16_bf16(
                    Af[s], Bf[s], acc, 0, 0, 0);
            // epilogue: lane's batch col = col0 + l31; acc regs cover 16 of
            // the 32 proxy rows (other 16 live in the hi^1 half-wave).
            float e0 = 0.f, e1 = 0.f, e2 = 0.f, e3 = 0.f;
            #pragma unroll
            for (int r = 0; r < 4; ++r) {
                e0 += FAST_EXP2(fmaf(acc[4*r+0], c1, c0));
                e1 += FAST_EXP2(fmaf(acc[4*r+1], c1, c0));
                e2 += FAST_EXP2(fmaf(acc[4*r+2], c1, c0));
                e3 += FAST_EXP2(fmaf(acc[4*r+3], c1, c0));
            }
            rs += (e0 + e1) + (e2 + e3);
        }
        rs += __shfl_xor(rs, 32, 64);            // combine the two row-halves
        if (hi == 0)
            atomicAdd(rs_base + col0 + l31, rs);
    }
}

// ---------- kernel 3: final lse + mean (4 blocks, atomicAdd out) ----------
__global__ __launch_bounds__(256) void final_kernel(
    const float* __restrict__ rowsum, const float* __restrict__ d_pos,
    float* __restrict__ out)
{
    int row = blockIdx.x * 256 + threadIdx.x;
    float tot = 0.f;
    #pragma unroll
    for (int s = 0; s < NSLICE; ++s)
        tot += rowsum[(size_t)s * BS + row];
    float dp = d_pos[row];
    const float PADC = 96.0f * exp2f(-18.0f * LOG2E);  // zero-pad rows
    float neg = tot - expf(-dp) - PADC;                // drop own column
    float val = dp + logf(fmaxf(neg, 1e-37f));
    #pragma unroll
    for (int m = 1; m < 64; m <<= 1) val += __shfl_xor(val, m, 64);
    __shared__ float red[4];
    if ((threadIdx.x & 63) == 0) red[threadIdx.x >> 6] = val;
    __syncthreads();
    if (threadIdx.x == 0) {
        float v = (red[0] + red[1]) + (red[2] + red[3]);
        atomicAdd(out, v * (1.0f / 1024.0f));
    }
}

extern "C" void kernel_launch(void* const* d_in, const int* in_sizes, int n_in,
                              void* d_out, int out_size, void* d_ws, size_t ws_size,
                              hipStream_t stream) {
    const float* batch   = (const float*)d_in[0];
    const float* proxies = (const float*)d_in[1];
    const int*   labels  = (const int*)d_in[2];
    float* out = (float*)d_out;

    char* ws = (char*)d_ws;
    unsigned short* A  = (unsigned short*)ws;                    //   262,144 B
    float* d_pos       = (float*)(ws + 262144);                  //     4,096 B
    float* rowsum      = (float*)(ws + 266240);                  //    65,536 B

    prep_kernel<<<128, 256, 0, stream>>>(batch, proxies, labels, A, d_pos, rowsum, out);
    main_kernel<<<NCH, 512, 0, stream>>>(proxies, A, rowsum);
    final_kernel<<<4, 256, 0, stream>>>(rowsum, d_pos, out);
}

// Round 2
// 142.992 us; speedup vs baseline: 1.4333x; 1.4333x over previous
//
#include <hip/hip_runtime.h>
#include <hip/hip_bf16.h>
#include <math.h>

#define BS 1024
#define D 128
#define NP 100000
#define PROWS 100096              // padded to multiple of 128 (96 zero rows)
#define CH 128                    // proxies per chunk/block
#define NCH (PROWS / CH)          // 782
#define NSLICE 16                 // rowsum slices (atomic contention / 16)
#define LOG2E 1.44269504088896340736f

typedef float f32x4 __attribute__((ext_vector_type(4)));
typedef float f32x16 __attribute__((ext_vector_type(16)));
typedef __bf16 bf16x8 __attribute__((ext_vector_type(8)));
typedef unsigned short u16x8 __attribute__((ext_vector_type(8)));

#if defined(__has_builtin)
#if __has_builtin(__builtin_amdgcn_exp2f)
#define FAST_EXP2(x) __builtin_amdgcn_exp2f(x)
#endif
#endif
#ifndef FAST_EXP2
#define FAST_EXP2(x) exp2f(x)
#endif

static __device__ __forceinline__ unsigned short f2bf(float x) {
    unsigned int u = __float_as_uint(x);
    return (unsigned short)((u + 0x7fffu + ((u >> 16) & 1u)) >> 16);  // RNE
}

// ---------- kernel 1: batch -> bf16 A, d_pos; zero rowsum slices + out ----
__global__ __launch_bounds__(256) void prep_kernel(
    const float* __restrict__ batch, const float* __restrict__ proxies,
    const int* __restrict__ labels, unsigned short* __restrict__ A,
    float* __restrict__ d_pos, float* __restrict__ rowsum,
    float* __restrict__ out)
{
    // zero the 16x1024 rowsum slices (128 blocks x 128 entries)
    if (threadIdx.x < 128) rowsum[blockIdx.x * 128 + threadIdx.x] = 0.f;
    if (blockIdx.x == 0 && threadIdx.x == 0) out[0] = 0.f;

    int wave = threadIdx.x >> 6, lane = threadIdx.x & 63;
    int sub = lane >> 5, c = lane & 31;
    int row = blockIdx.x * 8 + wave * 2 + sub;   // 0..1023
    float4 v = *(const float4*)(batch + (size_t)row * D + c * 4);
    float ss = v.x*v.x + v.y*v.y + v.z*v.z + v.w*v.w;
    #pragma unroll
    for (int m = 1; m < 32; m <<= 1) ss += __shfl_xor(ss, m, 64);
    float sc = 3.0f / fmaxf(sqrtf(ss), 1e-12f);
    ushort4 pk;
    pk.x = f2bf(v.x*sc); pk.y = f2bf(v.y*sc);
    pk.z = f2bf(v.z*sc); pk.w = f2bf(v.w*sc);
    *(ushort4*)(A + (size_t)row * D + c * 4) = pk;
    // d_pos in fp32: 18 - 2*(b.p_label)
    int lab = labels[row];
    float4 p4 = *(const float4*)(proxies + (size_t)lab * D + c * 4);
    float ps = p4.x*p4.x + p4.y*p4.y + p4.z*p4.z + p4.w*p4.w;
    #pragma unroll
    for (int m = 1; m < 32; m <<= 1) ps += __shfl_xor(ps, m, 64);
    float psc = 3.0f / fmaxf(sqrtf(ps), 1e-12f);
    float dt = (v.x*sc)*(p4.x*psc) + (v.y*sc)*(p4.y*psc)
             + (v.z*sc)*(p4.z*psc) + (v.w*sc)*(p4.w*psc);
    #pragma unroll
    for (int m = 1; m < 32; m <<= 1) dt += __shfl_xor(dt, m, 64);
    if (c == 0) d_pos[row] = 18.0f - 2.0f * dt;
}

// ---------- kernel 2: fused proxy-norm + GEMM + exp row-sums --------------
// 512 threads (8 waves), block = 128 proxies staged into XOR-swizzled LDS.
// mfma_f32_32x32x16_bf16 for 2x FLOP per operand byte; per-wave working
// set is Bf-cache 32 + Af 32 + acc 16 ~= 100 VGPRs.
// __launch_bounds__(512, 2): 2 blocks/CU -> 4 waves/SIMD -> 128-reg cap
// which FITS the working set. (512,4) empirically means 4 blocks/CU ->
// 8 waves/SIMD -> 64-reg cap -> 95 MB of scratch spill traffic. Do not.
// Each wave caches 32 batch columns x K=128 in registers (reloaded per
// outer iter from the L2-resident 256KB bf16 A matrix) and streams the
// 4 proxy subtiles from swizzled LDS. One atomicAdd per wave per outer.
__global__ __launch_bounds__(512, 2) void main_kernel(
    const float* __restrict__ proxies,
    const unsigned short* __restrict__ Abat,
    float* __restrict__ rowsum)          // [NSLICE][BS]
{
    __shared__ unsigned short Plds[CH * D];   // 32 KB
    const int tid = threadIdx.x;
    const int lane = tid & 63;
    const int wave = tid >> 6;
    const int l31 = lane & 31, hi = lane >> 5;
    const int chunk = blockIdx.x;

    // ---- staging: r = tid>>2 (0..127), q = tid&3 (32 floats each) --------
    {
        int r = tid >> 2, q = tid & 3;
        int pidx = chunk * CH + r;
        const float* src = proxies + (size_t)pidx * D + q * 32;
        float ss = 0.f;
        if (pidx < NP) {
            #pragma unroll
            for (int j = 0; j < 8; ++j) {
                float4 v = *(const float4*)(src + j * 4);
                ss += v.x*v.x + v.y*v.y + v.z*v.z + v.w*v.w;
            }
        }
        ss += __shfl_xor(ss, 1, 64);             // combine 4 quarters
        ss += __shfl_xor(ss, 2, 64);
        float sc = 3.0f / fmaxf(sqrtf(ss), 1e-12f);
        #pragma unroll
        for (int i2 = 0; i2 < 4; ++i2) {
            u16x8 w = (u16x8){0,0,0,0,0,0,0,0};
            if (pidx < NP) {
                float4 a = *(const float4*)(src + i2 * 8);      // L2 hit
                float4 b = *(const float4*)(src + i2 * 8 + 4);
                w[0] = f2bf(a.x*sc); w[1] = f2bf(a.y*sc);
                w[2] = f2bf(a.z*sc); w[3] = f2bf(a.w*sc);
                w[4] = f2bf(b.x*sc); w[5] = f2bf(b.y*sc);
                w[6] = f2bf(b.z*sc); w[7] = f2bf(b.w*sc);
            }
            int cl = q * 4 + i2;                 // 16B chunk index in row
            *(u16x8*)((char*)Plds + r * 256 + ((cl ^ (r & 15)) << 4)) = w;
        }
    }
    __syncthreads();

    const float c1 = 2.0f * LOG2E, c0 = -18.0f * LOG2E;
    float* rs_base = rowsum + (size_t)(chunk & (NSLICE - 1)) * BS;
    const int rx = l31 & 15;                     // swizzle key for A reads

    #pragma unroll 1
    for (int outer = 0; outer < 4; ++outer) {
        // this wave's 32 batch columns for this pass
        const int col0 = outer * 256 + wave * 32;
        // B-cache: 32 cols x K=128 -> 8 x bf16x8 = 32 VGPRs, loaded once.
        // lane layout per K-16 step s: col = l31, k = s*16 + hi*8 + j
        const unsigned short* bp = Abat + (size_t)(col0 + l31) * D + hi * 8;
        bf16x8 Bf[8];
        #pragma unroll
        for (int s = 0; s < 8; ++s)
            Bf[s] = *(const bf16x8*)(bp + s * 16);

        float rs = 0.f;
        #pragma unroll
        for (int st = 0; st < 4; ++st) {
            // A-frags for proxy subtile st: row = st*32 + l31,
            // k = s*16 + hi*8 + j  (16B chunk cl = s*2+hi, XOR-swizzled)
            const char* arow = (const char*)Plds + (st * 32 + l31) * 256;
            bf16x8 Af[8];
            #pragma unroll
            for (int s = 0; s < 8; ++s)
                Af[s] = *(const bf16x8*)(arow + (((s * 2 + hi) ^ rx) << 4));
            f32x16 acc = {0.f,0.f,0.f,0.f,0.f,0.f,0.f,0.f,
                          0.f,0.f,0.f,0.f,0.f,0.f,0.f,0.f};
            #pragma unroll
            for (int s = 0; s < 8; ++s)
                acc = __builtin_amdgcn_mfma_f32_32x32x16_bf16(
                    Af[s], Bf[s], acc, 0, 0, 0);
            // epilogue: lane's batch col = col0 + l31; acc regs cover 16 of
            // the 32 proxy rows (other 16 live in the hi^1 half-wave).
            float e0 = 0.f, e1 = 0.f, e2 = 0.f, e3 = 0.f;
            #pragma unroll
            for (int r = 0; r < 4; ++r) {
                e0 += FAST_EXP2(fmaf(acc[4*r+0], c1, c0));
                e1 += FAST_EXP2(fmaf(acc[4*r+1], c1, c0));
                e2 += FAST_EXP2(fmaf(acc[4*r+2], c1, c0));
                e3 += FAST_EXP2(fmaf(acc[4*r+3], c1, c0));
            }
            rs += (e0 + e1) + (e2 + e3);
        }
        rs += __shfl_xor(rs, 32, 64);            // combine the two row-halves
        if (hi == 0)
            atomicAdd(rs_base + col0 + l31, rs);
    }
}

// ---------- kernel 3: final lse + mean (4 blocks, atomicAdd out) ----------
__global__ __launch_bounds__(256) void final_kernel(
    const float* __restrict__ rowsum, const float* __restrict__ d_pos,
    float* __restrict__ out)
{
    int row = blockIdx.x * 256 + threadIdx.x;
    float tot = 0.f;
    #pragma unroll
    for (int s = 0; s < NSLICE; ++s)
        tot += rowsum[(size_t)s * BS + row];
    float dp = d_pos[row];
    const float PADC = 96.0f * exp2f(-18.0f * LOG2E);  // zero-pad rows
    float neg = tot - expf(-dp) - PADC;                // drop own column
    float val = dp + logf(fmaxf(neg, 1e-37f));
    #pragma unroll
    for (int m = 1; m < 64; m <<= 1) val += __shfl_xor(val, m, 64);
    __shared__ float red[4];
    if ((threadIdx.x & 63) == 0) red[threadIdx.x >> 6] = val;
    __syncthreads();
    if (threadIdx.x == 0) {
        float v = (red[0] + red[1]) + (red[2] + red[3]);
        atomicAdd(out, v * (1.0f / 1024.0f));
    }
}

extern "C" void kernel_launch(void* const* d_in, const int* in_sizes, int n_in,
                              void* d_out, int out_size, void* d_ws, size_t ws_size,
                              hipStream_t stream) {
    const float* batch   = (const float*)d_in[0];
    const float* proxies = (const float*)d_in[1];
    const int*   labels  = (const int*)d_in[2];
    float* out = (float*)d_out;

    char* ws = (char*)d_ws;
    unsigned short* A  = (unsigned short*)ws;                    //   262,144 B
    float* d_pos       = (float*)(ws + 262144);                  //     4,096 B
    float* rowsum      = (float*)(ws + 266240);                  //    65,536 B

    prep_kernel<<<128, 256, 0, stream>>>(batch, proxies, labels, A, d_pos, rowsum, out);
    main_kernel<<<NCH, 512, 0, stream>>>(proxies, A, rowsum);
    final_kernel<<<4, 256, 0, stream>>>(rowsum, d_pos, out);
}